// Round 1
// baseline (12957.248 us; speedup 1.0000x reference)
//
#include <hip/hip_runtime.h>
#include <hip/hip_bf16.h>

#define TT 512
#define BB 256
#define HH 512
#define FH 2048   // 4*H

typedef __attribute__((ext_vector_type(8))) short short8;
typedef __attribute__((ext_vector_type(4))) float f32x4;

__device__ __forceinline__ short f2bf(float f) {
  union { float f; unsigned u; } v; v.f = f;
  unsigned r = v.u + 0x7fffu + ((v.u >> 16) & 1u);   // RNE
  return (short)(r >> 16);
}

__device__ __forceinline__ float sigm(float x) {
  return 1.f / (1.f + __expf(-x));
}

// Build Wt[col][k] (bf16, col-major over K=1024: rows 0..511 = Wi, 512..1023 = Wh),
// init h (bf16) and c (fp32) state buffers from h0/c0.
__global__ void prep_kernel(const float* __restrict__ Wi, const float* __restrict__ Wh,
                            const float* __restrict__ h0, const float* __restrict__ c0,
                            short* __restrict__ Wt, short* __restrict__ hb,
                            float* __restrict__ cb) {
  int idx = blockIdx.x * blockDim.x + threadIdx.x;
  int stride = gridDim.x * blockDim.x;
  for (int i = idx; i < FH * 1024; i += stride) {
    int col = i >> 10;
    int k = i & 1023;
    float v = (k < HH) ? Wi[(size_t)k * FH + col] : Wh[(size_t)(k - HH) * FH + col];
    Wt[i] = f2bf(v);
  }
  for (int i = idx; i < BB * HH; i += stride) {
    hb[i] = f2bf(h0[i]);
    cb[i] = c0[i];
  }
}

// One LSTM step: gates = [x_t ; h_masked] @ Wt + b, then cell update.
// Wave tile: 32 batch-rows x 16 h-cols, all 4 gates. Grid (B/32, H/16) = (8,32).
__global__ __launch_bounds__(64) void lstm_step(
    const float* __restrict__ xt,    // (B,H) fp32 slice of inputs at t
    const int* __restrict__ rst,     // (B,) resets at t
    const float* __restrict__ bias,  // (2048,)
    const short* __restrict__ Wt,    // (2048,1024) bf16 bits
    const short* __restrict__ hin,   // (B,H) bf16 bits
    short* __restrict__ hout,        // (B,H) bf16 bits
    float* __restrict__ cbuf,        // (B,H) fp32
    float* __restrict__ ys)          // (B,H) fp32 output slice
{
  const int lane = threadIdx.x;
  const int lc = lane & 15;
  const int kg = lane >> 4;          // 0..3
  const int r0 = blockIdx.x * 32;
  const int h0 = blockIdx.y * 16;
  const int kb0 = kg * 8;

  f32x4 acc[2][4];
  for (int g = 0; g < 4; ++g) {
    float bv = bias[g * HH + h0 + lc];
    f32x4 b4 = {bv, bv, bv, bv};
    acc[0][g] = b4;
    acc[1][g] = b4;
  }

  const int rowA0 = r0 + lc;
  const int rowA1 = r0 + 16 + lc;
  const short* wbase = Wt + (size_t)(h0 + lc) * 1024 + kb0;

  // ---- x part: global K 0..511 ----
  for (int kk = 0; kk < 16; ++kk) {
    int k = kk * 32 + kb0;
    const float* p0 = xt + (size_t)rowA0 * HH + k;
    const float* p1 = xt + (size_t)rowA1 * HH + k;
    f32x4 u0 = *(const f32x4*)p0;
    f32x4 u1 = *(const f32x4*)(p0 + 4);
    f32x4 v0 = *(const f32x4*)p1;
    f32x4 v1 = *(const f32x4*)(p1 + 4);
    short8 a0, a1;
    for (int e = 0; e < 4; ++e) {
      a0[e] = f2bf(u0[e]); a0[e + 4] = f2bf(u1[e]);
      a1[e] = f2bf(v0[e]); a1[e + 4] = f2bf(v1[e]);
    }
    for (int g = 0; g < 4; ++g) {
      short8 bf = *(const short8*)(wbase + (size_t)g * HH * 1024 + kk * 32);
      acc[0][g] = __builtin_amdgcn_mfma_f32_16x16x32_bf16(a0, bf, acc[0][g], 0, 0, 0);
      acc[1][g] = __builtin_amdgcn_mfma_f32_16x16x32_bf16(a1, bf, acc[1][g], 0, 0, 0);
    }
  }

  // ---- h part: global K 512..1023, with reset masking of h ----
  const bool rm0 = rst[rowA0] != 0;
  const bool rm1 = rst[rowA1] != 0;
  const short8 zero = {0, 0, 0, 0, 0, 0, 0, 0};
  for (int kk = 0; kk < 16; ++kk) {
    int k = kk * 32 + kb0;
    short8 a0 = rm0 ? zero : *(const short8*)(hin + (size_t)rowA0 * HH + k);
    short8 a1 = rm1 ? zero : *(const short8*)(hin + (size_t)rowA1 * HH + k);
    for (int g = 0; g < 4; ++g) {
      short8 bf = *(const short8*)(wbase + (size_t)g * HH * 1024 + 512 + kk * 32);
      acc[0][g] = __builtin_amdgcn_mfma_f32_16x16x32_bf16(a0, bf, acc[0][g], 0, 0, 0);
      acc[1][g] = __builtin_amdgcn_mfma_f32_16x16x32_bf16(a1, bf, acc[1][g], 0, 0, 0);
    }
  }

  // ---- epilogue: C/D layout col=lane&15, row=(lane>>4)*4+j ----
  const int hc = h0 + lc;
  for (int m = 0; m < 2; ++m) {
    int rbase = r0 + m * 16 + kg * 4;
    for (int j = 0; j < 4; ++j) {
      int row = rbase + j;
      float gi = acc[m][0][j];
      float gf = acc[m][1][j];
      float gg = acc[m][2][j];
      float go = acc[m][3][j];
      float cold = (rst[row] != 0) ? 0.f : cbuf[(size_t)row * HH + hc];
      float cn = sigm(gf) * cold + sigm(gi) * tanhf(gg);
      float hn = sigm(go) * tanhf(cn);
      cbuf[(size_t)row * HH + hc] = cn;
      hout[(size_t)row * HH + hc] = f2bf(hn);
      ys[(size_t)row * HH + hc] = hn;
    }
  }
}

// c_f and h_f tails of d_out (h_f = ys[T-1]).
__global__ void finalize_kernel(const float* __restrict__ cbuf, float* __restrict__ out) {
  int i = blockIdx.x * blockDim.x + threadIdx.x;
  if (i < BB * HH) {
    size_t base = (size_t)TT * BB * HH;
    out[base + i] = cbuf[i];
    out[base + BB * HH + i] = out[(size_t)(TT - 1) * BB * HH + i];
  }
}

extern "C" void kernel_launch(void* const* d_in, const int* in_sizes, int n_in,
                              void* d_out, int out_size, void* d_ws, size_t ws_size,
                              hipStream_t stream) {
  const float* x      = (const float*)d_in[0];
  const int*   resets = (const int*)d_in[1];
  const float* c0     = (const float*)d_in[2];
  const float* h0     = (const float*)d_in[3];
  const float* Wi     = (const float*)d_in[4];
  const float* Wh     = (const float*)d_in[5];
  const float* bias   = (const float*)d_in[6];
  float* out = (float*)d_out;

  char* ws = (char*)d_ws;
  short* Wt  = (short*)ws;                                  // 4 MiB
  short* hb0 = (short*)(ws + (4u << 20));                   // 256 KiB
  short* hb1 = hb0 + BB * HH;                               // 256 KiB
  float* cb  = (float*)(ws + (4u << 20) + (512u << 10));    // 512 KiB

  prep_kernel<<<1024, 256, 0, stream>>>(Wi, Wh, h0, c0, Wt, hb0, cb);

  for (int t = 0; t < TT; ++t) {
    const short* hin = (t & 1) ? hb1 : hb0;
    short* hout      = (t & 1) ? hb0 : hb1;
    lstm_step<<<dim3(8, 32), 64, 0, stream>>>(
        x + (size_t)t * BB * HH, resets + (size_t)t * BB, bias, Wt,
        hin, hout, cb, out + (size_t)t * BB * HH);
  }

  finalize_kernel<<<(BB * HH + 255) / 256, 256, 0, stream>>>(cb, out);
}

// Round 2
// 5924.467 us; speedup vs baseline: 2.1871x; 2.1871x over previous
//
#include <hip/hip_runtime.h>

#define TT 512
#define BB 256
#define HH 512
#define FH 2048   // 4*H

typedef __attribute__((ext_vector_type(8))) short short8;
typedef __attribute__((ext_vector_type(4))) short short4v;
typedef __attribute__((ext_vector_type(4))) float f32x4;

__device__ __forceinline__ short f2bf(float f) {
  union { float f; unsigned u; } v; v.f = f;
  unsigned r = v.u + 0x7fffu + ((v.u >> 16) & 1u);   // RNE
  return (short)(r >> 16);
}

__device__ __forceinline__ float sigm(float x) {
  return 1.f / (1.f + __expf(-x));
}

// Build WiT[col][k], WhT[col][k] (bf16, col-major over K=512), init h (bf16), c (fp32).
__global__ void prep_kernel(const float* __restrict__ Wi, const float* __restrict__ Wh,
                            const float* __restrict__ h0, const float* __restrict__ c0,
                            short* __restrict__ WiT, short* __restrict__ WhT,
                            short* __restrict__ hb, float* __restrict__ cb) {
  int idx = blockIdx.x * blockDim.x + threadIdx.x;
  int stride = gridDim.x * blockDim.x;
  for (int i = idx; i < FH * HH; i += stride) {
    int col = i >> 9;
    int k = i & 511;
    WiT[i] = f2bf(Wi[(size_t)k * FH + col]);
    WhT[i] = f2bf(Wh[(size_t)k * FH + col]);
  }
  for (int i = idx; i < BB * HH; i += stride) {
    hb[i] = f2bf(h0[i]);
    cb[i] = c0[i];
  }
}

// Gx[row][col] = X[rowBase+row][:] @ WiT[col][:] + bias[col], for a chunk of rows.
// Block: 256 thr (4 waves), tile 32 rows x 256 cols. Grid (chunkRows/32, 8).
__global__ __launch_bounds__(256) void precomp_kernel(
    const float* __restrict__ X, const short* __restrict__ WiT,
    const float* __restrict__ bias, float* __restrict__ Gx, int rowBase) {
  __shared__ short lx[32 * 520];   // padded stride breaks bank conflicts
  const int tid = threadIdx.x;
  const int rb = blockIdx.x * 32;
  const size_t grow = (size_t)(rowBase + rb);

  for (int e = tid * 4; e < 32 * 512; e += 1024) {
    int row = e >> 9;
    int col = e & 511;
    f32x4 v = *(const f32x4*)(X + (grow + row) * 512 + col);
    short4v s = { f2bf(v[0]), f2bf(v[1]), f2bf(v[2]), f2bf(v[3]) };
    *(short4v*)(&lx[row * 520 + col]) = s;
  }
  __syncthreads();

  const int wid = tid >> 6;
  const int lane = tid & 63;
  const int lc = lane & 15;
  const int kg = lane >> 4;
  const int n0 = blockIdx.y * 256 + wid * 64;

  f32x4 acc[2][4] = {};
#pragma unroll
  for (int kk = 0; kk < 16; ++kk) {
    const int ko = kk * 32 + kg * 8;
    short8 a0 = *(const short8*)(&lx[lc * 520 + ko]);
    short8 a1 = *(const short8*)(&lx[(16 + lc) * 520 + ko]);
#pragma unroll
    for (int nf = 0; nf < 4; ++nf) {
      const short8 b = *(const short8*)(WiT + (size_t)(n0 + nf * 16 + lc) * 512 + ko);
      acc[0][nf] = __builtin_amdgcn_mfma_f32_16x16x32_bf16(a0, b, acc[0][nf], 0, 0, 0);
      acc[1][nf] = __builtin_amdgcn_mfma_f32_16x16x32_bf16(a1, b, acc[1][nf], 0, 0, 0);
    }
  }

  for (int nf = 0; nf < 4; ++nf) {
    int col = n0 + nf * 16 + lc;
    float bv = bias[col];
    for (int m = 0; m < 2; ++m)
      for (int j = 0; j < 4; ++j) {
        int row = rb + m * 16 + kg * 4 + j;
        Gx[(size_t)row * FH + col] = acc[m][nf][j] + bv;
      }
  }
}

// One step, with precomputed Gx: gates = Gx[t] + h_masked @ WhT. Grid (16,32), 1 wave.
__global__ __launch_bounds__(64) void lstm_step2(
    const int* __restrict__ rst, const short* __restrict__ WhT,
    const float* __restrict__ gx,    // (B,2048) slice for this t (bias included)
    const short* __restrict__ hin, short* __restrict__ hout,
    float* __restrict__ cbuf, float* __restrict__ ys) {
  const int lane = threadIdx.x;
  const int lc = lane & 15;
  const int kg = lane >> 4;
  const int r0 = blockIdx.x * 16;
  const int h0 = blockIdx.y * 16;
  const int hc = h0 + lc;

  // prefetch epilogue inputs so their latency hides under the MFMA loop
  float gxv[4][4], coldv[4];
  int rstj[4];
#pragma unroll
  for (int j = 0; j < 4; ++j) {
    int row = r0 + kg * 4 + j;
    rstj[j] = rst[row];
    coldv[j] = cbuf[(size_t)row * HH + hc];
#pragma unroll
    for (int g = 0; g < 4; ++g) gxv[g][j] = gx[(size_t)row * FH + g * HH + hc];
  }

  const int rowA = r0 + lc;
  const bool rm = rst[rowA] != 0;
  const short8 zero = {};
  f32x4 acc[4] = {};
#pragma unroll
  for (int kk = 0; kk < 16; ++kk) {
    const int ko = kk * 32 + kg * 8;
    short8 a = rm ? zero : *(const short8*)(hin + (size_t)rowA * HH + ko);
#pragma unroll
    for (int g = 0; g < 4; ++g) {
      const short8 b = *(const short8*)(WhT + (size_t)(g * HH + h0 + lc) * HH + ko);
      acc[g] = __builtin_amdgcn_mfma_f32_16x16x32_bf16(a, b, acc[g], 0, 0, 0);
    }
  }

#pragma unroll
  for (int j = 0; j < 4; ++j) {
    int row = r0 + kg * 4 + j;
    float gi = acc[0][j] + gxv[0][j];
    float gf = acc[1][j] + gxv[1][j];
    float gg = acc[2][j] + gxv[2][j];
    float go = acc[3][j] + gxv[3][j];
    float cold = rstj[j] ? 0.f : coldv[j];
    float cn = sigm(gf) * cold + sigm(gi) * tanhf(gg);
    float hn = sigm(go) * tanhf(cn);
    cbuf[(size_t)row * HH + hc] = cn;
    hout[(size_t)row * HH + hc] = f2bf(hn);
    ys[(size_t)row * HH + hc] = hn;
  }
}

// Fallback when ws is too small for Gx: full K=1024 per step (x part on the fly).
__global__ __launch_bounds__(64) void lstm_step_fullk(
    const float* __restrict__ xt, const int* __restrict__ rst,
    const float* __restrict__ bias, const short* __restrict__ WiT,
    const short* __restrict__ WhT, const short* __restrict__ hin,
    short* __restrict__ hout, float* __restrict__ cbuf, float* __restrict__ ys) {
  const int lane = threadIdx.x;
  const int lc = lane & 15;
  const int kg = lane >> 4;
  const int r0 = blockIdx.x * 16;
  const int h0 = blockIdx.y * 16;
  const int hc = h0 + lc;

  float coldv[4];
  int rstj[4];
#pragma unroll
  for (int j = 0; j < 4; ++j) {
    int row = r0 + kg * 4 + j;
    rstj[j] = rst[row];
    coldv[j] = cbuf[(size_t)row * HH + hc];
  }

  const int rowA = r0 + lc;
  const bool rm = rst[rowA] != 0;
  const short8 zero = {};
  f32x4 acc[4] = {};
#pragma unroll
  for (int kk = 0; kk < 16; ++kk) {
    const int ko = kk * 32 + kg * 8;
    f32x4 u0 = *(const f32x4*)(xt + (size_t)rowA * HH + ko);
    f32x4 u1 = *(const f32x4*)(xt + (size_t)rowA * HH + ko + 4);
    short8 a;
#pragma unroll
    for (int e = 0; e < 4; ++e) { a[e] = f2bf(u0[e]); a[e + 4] = f2bf(u1[e]); }
#pragma unroll
    for (int g = 0; g < 4; ++g) {
      const short8 b = *(const short8*)(WiT + (size_t)(g * HH + h0 + lc) * HH + ko);
      acc[g] = __builtin_amdgcn_mfma_f32_16x16x32_bf16(a, b, acc[g], 0, 0, 0);
    }
  }
#pragma unroll
  for (int kk = 0; kk < 16; ++kk) {
    const int ko = kk * 32 + kg * 8;
    short8 a = rm ? zero : *(const short8*)(hin + (size_t)rowA * HH + ko);
#pragma unroll
    for (int g = 0; g < 4; ++g) {
      const short8 b = *(const short8*)(WhT + (size_t)(g * HH + h0 + lc) * HH + ko);
      acc[g] = __builtin_amdgcn_mfma_f32_16x16x32_bf16(a, b, acc[g], 0, 0, 0);
    }
  }

#pragma unroll
  for (int j = 0; j < 4; ++j) {
    int row = r0 + kg * 4 + j;
    float gi = acc[0][j] + bias[0 * HH + hc];
    float gf = acc[1][j] + bias[1 * HH + hc];
    float gg = acc[2][j] + bias[2 * HH + hc];
    float go = acc[3][j] + bias[3 * HH + hc];
    float cold = rstj[j] ? 0.f : coldv[j];
    float cn = sigm(gf) * cold + sigm(gi) * tanhf(gg);
    float hn = sigm(go) * tanhf(cn);
    cbuf[(size_t)row * HH + hc] = cn;
    hout[(size_t)row * HH + hc] = f2bf(hn);
    ys[(size_t)row * HH + hc] = hn;
  }
}

__global__ void finalize_kernel(const float* __restrict__ cbuf, float* __restrict__ out) {
  int i = blockIdx.x * blockDim.x + threadIdx.x;
  if (i < BB * HH) {
    size_t base = (size_t)TT * BB * HH;
    out[base + i] = cbuf[i];
    out[base + BB * HH + i] = out[(size_t)(TT - 1) * BB * HH + i];
  }
}

extern "C" void kernel_launch(void* const* d_in, const int* in_sizes, int n_in,
                              void* d_out, int out_size, void* d_ws, size_t ws_size,
                              hipStream_t stream) {
  const float* x      = (const float*)d_in[0];
  const int*   resets = (const int*)d_in[1];
  const float* c0     = (const float*)d_in[2];
  const float* h0     = (const float*)d_in[3];
  const float* Wi     = (const float*)d_in[4];
  const float* Wh     = (const float*)d_in[5];
  const float* bias   = (const float*)d_in[6];
  float* out = (float*)d_out;

  char* ws = (char*)d_ws;
  short* WiT = (short*)ws;                                  // 2 MiB
  short* WhT = (short*)(ws + (2u << 20));                   // 2 MiB
  short* hb0 = (short*)(ws + (4u << 20));                   // 256 KiB
  short* hb1 = hb0 + BB * HH;                               // 256 KiB
  float* cb  = (float*)(ws + (4u << 20) + (512u << 10));    // 512 KiB
  const size_t base = (size_t)5 << 20;

  const size_t perT = (size_t)BB * FH * 4;                  // 2 MiB per step of Gx
  int chunkT = 0;
  if (ws_size > base) chunkT = (int)((ws_size - base) / perT);
  if (chunkT > TT) chunkT = TT;

  prep_kernel<<<1024, 256, 0, stream>>>(Wi, Wh, h0, c0, WiT, WhT, hb0, cb);

  if (chunkT >= 1) {
    float* Gx = (float*)(ws + base);
    for (int t0 = 0; t0 < TT; t0 += chunkT) {
      int ct = (TT - t0 < chunkT) ? (TT - t0) : chunkT;
      precomp_kernel<<<dim3(ct * 8, 8), 256, 0, stream>>>(x, WiT, bias, Gx, t0 * BB);
      for (int t = t0; t < t0 + ct; ++t) {
        const short* hin = (t & 1) ? hb1 : hb0;
        short* hout      = (t & 1) ? hb0 : hb1;
        lstm_step2<<<dim3(16, 32), 64, 0, stream>>>(
            resets + (size_t)t * BB, WhT, Gx + (size_t)(t - t0) * BB * FH,
            hin, hout, cb, out + (size_t)t * BB * HH);
      }
    }
  } else {
    for (int t = 0; t < TT; ++t) {
      const short* hin = (t & 1) ? hb1 : hb0;
      short* hout      = (t & 1) ? hb0 : hb1;
      lstm_step_fullk<<<dim3(16, 32), 64, 0, stream>>>(
          x + (size_t)t * BB * HH, resets + (size_t)t * BB, bias, WiT, WhT,
          hin, hout, cb, out + (size_t)t * BB * HH);
    }
  }

  finalize_kernel<<<(BB * HH + 255) / 256, 256, 0, stream>>>(cb, out);
}